// Round 1
// baseline (1237.108 us; speedup 1.0000x reference)
//
#include <hip/hip_runtime.h>

#define Tn 200
#define Dn 64
#define Hn 64
// K = Dn + Hn = 128

__device__ __forceinline__ float fast_sigmoid(float v) {
    // 1/(1+e^-v); stable: v<<0 -> exp(+big)=inf -> rcp(inf)=0; v>>0 -> exp(-big)=0 -> 1
    return __builtin_amdgcn_rcpf(1.0f + __expf(-v));
}

__device__ __forceinline__ float fast_tanh(float v) {
    // 1 - 2/(1+e^{2v}); stable at both ends
    return 1.0f - 2.0f * __builtin_amdgcn_rcpf(1.0f + __expf(2.0f * v));
}

__global__ __launch_bounds__(64, 1)
void augru_kernel(const float* __restrict__ x,     // [B,T,D]
                  const int*   __restrict__ slen,  // [B]
                  const float* __restrict__ att,   // [B,T]
                  const float* __restrict__ gk,    // [128][128] (cols: r|u)
                  const float* __restrict__ gb,    // [128]
                  const float* __restrict__ ck,    // [128][64]
                  const float* __restrict__ cb,    // [64]
                  float* __restrict__ out)         // [B,T,H]
{
    const int b = blockIdx.x;
    const int j = threadIdx.x;  // 0..63 == output column

    __shared__ float s_h[Hn];
    __shared__ float s_rh[Hn];

    // Register-resident weight columns for this lane.
    float wr[128], wu[128], wc[128];
#pragma unroll
    for (int k = 0; k < 128; ++k) {
        wr[k] = gk[k * 128 + j];
        wu[k] = gk[k * 128 + 64 + j];
    }
#pragma unroll
    for (int k = 0; k < 128; ++k) {
        wc[k] = ck[k * 64 + j];
    }

    const float br = gb[j];
    const float bu = gb[64 + j];
    const float bc = cb[j];
    const int len = slen[b];

    const float* xrow = x + (size_t)b * Tn * Dn;
    const float* arow = att + (size_t)b * Tn;
    float*       orow = out + (size_t)b * Tn * Hn;

    float h = 0.0f;

    for (int t = 0; t < len; ++t) {
        const float4* xv = (const float4*)(xrow + t * Dn);  // lane-uniform broadcast loads
        const float a = arow[t];

        s_h[j] = h;
        __syncthreads();

        // ---- gates: sigmoid([x,h] @ Wg + bg), split r|u ----
        float r0 = br, r1 = 0.0f, u0 = bu, u1 = 0.0f;
#pragma unroll
        for (int kk = 0; kk < 16; ++kk) {
            const float4 q = xv[kk];
            const int k = kk * 4;
            r0 = fmaf(q.x, wr[k],     r0);
            r1 = fmaf(q.y, wr[k + 1], r1);
            r0 = fmaf(q.z, wr[k + 2], r0);
            r1 = fmaf(q.w, wr[k + 3], r1);
            u0 = fmaf(q.x, wu[k],     u0);
            u1 = fmaf(q.y, wu[k + 1], u1);
            u0 = fmaf(q.z, wu[k + 2], u0);
            u1 = fmaf(q.w, wu[k + 3], u1);
        }
        const float4* hv = (const float4*)s_h;  // broadcast reads
#pragma unroll
        for (int kk = 0; kk < 16; ++kk) {
            const float4 q = hv[kk];
            const int k = 64 + kk * 4;
            r0 = fmaf(q.x, wr[k],     r0);
            r1 = fmaf(q.y, wr[k + 1], r1);
            r0 = fmaf(q.z, wr[k + 2], r0);
            r1 = fmaf(q.w, wr[k + 3], r1);
            u0 = fmaf(q.x, wu[k],     u0);
            u1 = fmaf(q.y, wu[k + 1], u1);
            u0 = fmaf(q.z, wu[k + 2], u0);
            u1 = fmaf(q.w, wu[k + 3], u1);
        }
        const float rg = fast_sigmoid(r0 + r1);
        const float ug = fast_sigmoid(u0 + u1);

        s_rh[j] = rg * h;
        __syncthreads();

        // ---- candidate: tanh([x, r*h] @ Wc + bc) ----
        float c0 = bc, c1 = 0.0f;
#pragma unroll
        for (int kk = 0; kk < 16; ++kk) {
            const float4 q = xv[kk];
            const int k = kk * 4;
            c0 = fmaf(q.x, wc[k],     c0);
            c1 = fmaf(q.y, wc[k + 1], c1);
            c0 = fmaf(q.z, wc[k + 2], c0);
            c1 = fmaf(q.w, wc[k + 3], c1);
        }
        const float4* rhv = (const float4*)s_rh;  // broadcast reads
#pragma unroll
        for (int kk = 0; kk < 16; ++kk) {
            const float4 q = rhv[kk];
            const int k = 64 + kk * 4;
            c0 = fmaf(q.x, wc[k],     c0);
            c1 = fmaf(q.y, wc[k + 1], c1);
            c0 = fmaf(q.z, wc[k + 2], c0);
            c1 = fmaf(q.w, wc[k + 3], c1);
        }
        const float cg = fast_tanh(c0 + c1);

        const float uh = (1.0f - a) * ug;           // attention-modulated update gate
        h = uh * h + (1.0f - uh) * cg;              // t < len here, so always valid
        orow[t * Hn + j] = h;

        __syncthreads();  // WAR: protect s_h / s_rh before next iteration's writes
    }

    // ---- zero tail: out[b, len:T, :] = 0 (contiguous region) ----
    float4 z;
    z.x = z.y = z.z = z.w = 0.0f;
    float* tail = orow + len * Hn;
    const int total = (Tn - len) * Hn;
    for (int i = j * 4; i < total; i += 64 * 4) {
        *(float4*)(tail + i) = z;
    }
}

extern "C" void kernel_launch(void* const* d_in, const int* in_sizes, int n_in,
                              void* d_out, int out_size, void* d_ws, size_t ws_size,
                              hipStream_t stream) {
    const float* x    = (const float*)d_in[0];  // rnn_input [2048,200,64]
    const int*   slen = (const int*)  d_in[1];  // sequence_length [2048]
    const float* att  = (const float*)d_in[2];  // att_score [2048,200,1]
    const float* gk   = (const float*)d_in[3];  // gate_kernel [128,128]
    const float* gb   = (const float*)d_in[4];  // gate_bias [128]
    const float* ck   = (const float*)d_in[5];  // cand_kernel [128,64]
    const float* cb   = (const float*)d_in[6];  // cand_bias [64]
    float* out = (float*)d_out;

    const int B = in_sizes[1];  // 2048
    augru_kernel<<<B, 64, 0, stream>>>(x, slen, att, gk, gb, ck, cb, out);
}